// Round 1
// 219.384 us; speedup vs baseline: 1.0059x; 1.0059x over previous
//
#include <hip/hip_runtime.h>
#include <hip/hip_fp16.h>

// Problem constants (from reference setup_inputs)
#define B_   2
#define C_   256
#define H_   200
#define W_   304
#define HW_  60800       // H_*W_
#define N_   512
#define OH_  7
#define OW_  7
#define POS_ 49          // OH_*OW_
#define CPB_ 12544       // C_*POS_  (outputs per box)

#define HC_   128        // channels per gather block (c-half)
#define HCPB_ 6272       // HC_*POS_ (outputs per half-box)
#define GP2_  132        // gather staging pitch (halves), 8B aligned

// ---------------------------------------------------------------------------
// Pass 1 v5 (UNCHANGED): transpose + fp32->fp16: (B, C, HW) -> (B, HW, C).
// Tile = 128 hw x 128 c (c-half per block). Un-padded 32 KB LDS tile with
// XOR quad swizzle: q' = q ^ 2*((row>>2)&7).
// ---------------------------------------------------------------------------
__global__ __launch_bounds__(256) void transpose_f16_v5(
    const float* __restrict__ fm,   // (B, C, HW) fp32
    ushort* __restrict__ fmT)       // (B, HW, C) fp16 bits
{
    __shared__ ushort tile[128 * 128];   // [hw][c'], 32 KB, swizzled quads

    const int blk = blockIdx.x;          // 0..1899
    const int b   = blk / 950;
    const int r0  = blk - b * 950;
    const int ch  = r0 / 475;            // c-half 0/1
    const int hwT = r0 - ch * 475;       // 0..474
    const int hw0 = hwT * 128;
    const int c0  = ch * 128;

    const int t = threadIdx.x;

    const float* __restrict__ src = fm + ((size_t)(b * C_ + c0)) * HW_ + hw0;

    // ---- load phase: 4 patches of (4c x 4hw)/thread; wave inst = 2x512B rows
    float4 rg[4][4];
    #pragma unroll
    for (int i = 0; i < 4; ++i) {
        const int p  = i * 256 + t;
        const int hq = p & 31;           // hw quad 0..31
        const int cq = p >> 5;           // c  quad 0..31
        #pragma unroll
        for (int j = 0; j < 4; ++j)
            rg[i][j] = *(const float4*)(src + (size_t)(cq * 4 + j) * HW_ + hq * 4);
    }

    // ---- convert + 4x4 register transpose -> ds_write_b64 (swizzled)
    #pragma unroll
    for (int i = 0; i < 4; ++i) {
        const int p  = i * 256 + t;
        const int hq = p & 31;
        const int cq = p >> 5;
        const int qs = cq ^ ((hq & 7) << 1);   // f(row)=2*((row>>2)&7), row>>2==hq
        #pragma unroll
        for (int j2 = 0; j2 < 4; ++j2) {       // hw element within the quad
            const int row = hq * 4 + j2;
            ushort4 u;
            u.x = __half_as_ushort(__float2half_rn(((const float*)&rg[i][0])[j2]));
            u.y = __half_as_ushort(__float2half_rn(((const float*)&rg[i][1])[j2]));
            u.z = __half_as_ushort(__float2half_rn(((const float*)&rg[i][2])[j2]));
            u.w = __half_as_ushort(__float2half_rn(((const float*)&rg[i][3])[j2]));
            *(ushort4*)&tile[row * 128 + qs * 4] = u;
        }
    }
    __syncthreads();

    // ---- store phase: 16B/lane; wave inst = 4 rows x 256 B
    ushort* __restrict__ dst = fmT + ((size_t)(b * HW_ + hw0)) * C_ + c0;

    #pragma unroll
    for (int s = 0; s < 8; ++s) {
        const int g   = s * 256 + t;     // 0..2047
        const int row = g >> 4;          // 0..127
        const int m   = g & 15;          // ushort8 block within the 128-c half
        const int msw = m ^ ((row >> 2) & 7);   // un-swizzle (2m ^ 2g = 2(m^g))
        const uint4 v = *(const uint4*)&tile[row * 128 + msw * 8];
        *(uint4*)(dst + (size_t)row * C_ + m * 8) = v;
    }
}

// ---------------------------------------------------------------------------
// Pass 2 v3: gather, split per channel-half. One block per (box, c-half):
// 2048 blocks (= exactly 8/CU), LDS 14.2 KB -> 32 waves/CU (was 20).
// Pos loop is a compile-time 7-trip predicated unroll so the compiler can
// hoist all ~28 independent 8B tap loads and pipeline the FMAs under them.
// Same tap access pattern as v2 (each wave instr = 2 x 256B full segments),
// identical numerics (fp16 round before LDS staging).
// ---------------------------------------------------------------------------
__global__ __launch_bounds__(256) void gather_f16_v3(
    const ushort* __restrict__ fmT,   // (B, HW, C) fp16 bits
    const float* __restrict__ boxes,  // (B, N, 5)
    float* __restrict__ out)          // (B*N, C, 7, 7) fp32
{
    __shared__ int4   sOff[POS_];             // tap offsets (pre-scaled by C_)
    __shared__ float4 sWgt[POS_];             // weights with validity folded
    __shared__ ushort sVal[POS_ * GP2_];      // [pos][c_loc] fp16, 12.9 KB

    const int blk = blockIdx.x;       // 0 .. 2*B*N-1
    const int bn  = blk >> 1;         // box index
    const int ch  = blk & 1;          // c-half 0/1
    const int b   = bn >> 9;          // N_ = 512
    const int tid = threadIdx.x;

    if (tid < POS_) {
        const float* bx = boxes + (size_t)bn * 5;
        const float cx = bx[0], cy = bx[1], w = bx[2], h = bx[3], ang = bx[4];

        const float rad = -ang * 0.017453292519943295f;   // -pi/180
        const float cr = cosf(rad), sr = sinf(rad);

        const float a00 =  w * (1.0f / W_) * cr;
        const float a01 = -h * (1.0f / H_) * sr;
        const float a02 =  2.0f * cx * (1.0f / W_) - 1.0f;
        const float a10 =  w * (1.0f / W_) * sr;
        const float a11 =  h * (1.0f / H_) * cr;
        const float a12 =  2.0f * cy * (1.0f / H_) - 1.0f;

        const int py = tid / OW_;
        const int px = tid - py * OW_;
        const float xs = (2.0f * (float)px + 1.0f) / (float)OW_ - 1.0f;
        const float ys = (2.0f * (float)py + 1.0f) / (float)OH_ - 1.0f;

        const float gx = a00 * xs + a01 * ys + a02;
        const float gy = a10 * xs + a11 * ys + a12;

        const float ix = ((gx + 1.0f) * (float)W_ - 1.0f) * 0.5f;
        const float iy = ((gy + 1.0f) * (float)H_ - 1.0f) * 0.5f;

        const float x0f = floorf(ix), y0f = floorf(iy);
        const float wx1 = ix - x0f,  wy1 = iy - y0f;
        const float wx0 = 1.0f - wx1, wy0 = 1.0f - wy1;
        const float x1f = x0f + 1.0f, y1f = y0f + 1.0f;

        const float vx0 = (x0f >= 0.0f && x0f <= (float)(W_ - 1)) ? 1.0f : 0.0f;
        const float vx1 = (x1f >= 0.0f && x1f <= (float)(W_ - 1)) ? 1.0f : 0.0f;
        const float vy0 = (y0f >= 0.0f && y0f <= (float)(H_ - 1)) ? 1.0f : 0.0f;
        const float vy1 = (y1f >= 0.0f && y1f <= (float)(H_ - 1)) ? 1.0f : 0.0f;

        const int xi0 = (int)fminf(fmaxf(x0f, 0.0f), (float)(W_ - 1));
        const int xi1 = (int)fminf(fmaxf(x1f, 0.0f), (float)(W_ - 1));
        const int yi0 = (int)fminf(fmaxf(y0f, 0.0f), (float)(H_ - 1));
        const int yi1 = (int)fminf(fmaxf(y1f, 0.0f), (float)(H_ - 1));

        sOff[tid] = make_int4((yi0 * W_ + xi0) * C_, (yi0 * W_ + xi1) * C_,
                              (yi1 * W_ + xi0) * C_, (yi1 * W_ + xi1) * C_);
        sWgt[tid] = make_float4(wy0 * wx0 * (vy0 * vx0),
                                wy0 * wx1 * (vy0 * vx1),
                                wy1 * wx0 * (vy1 * vx0),
                                wy1 * wx1 * (vy1 * vx1));
    }
    __syncthreads();

    const int cl = (tid & 31) * 4;      // local channel 0..124 (ushort4)
    const int g  = tid >> 5;            // pos group 0..7

    const ushort* __restrict__ fb =
        fmT + (size_t)b * HW_ * C_ + (size_t)(ch * HC_) + cl;

    #pragma unroll
    for (int k = 0; k < 7; ++k) {
        const int pos = g + k * 8;      // g=0 gets 7 positions, others 6
        if (pos < POS_) {
            const int4   o  = sOff[pos];
            const float4 wv = sWgt[pos];

            const ushort4 q0 = *(const ushort4*)(fb + o.x);
            const ushort4 q1 = *(const ushort4*)(fb + o.y);
            const ushort4 q2 = *(const ushort4*)(fb + o.z);
            const ushort4 q3 = *(const ushort4*)(fb + o.w);

            ushort4 u;
            {
                const float a = wv.x * __half2float(__ushort_as_half(q0.x))
                              + wv.y * __half2float(__ushort_as_half(q1.x))
                              + wv.z * __half2float(__ushort_as_half(q2.x))
                              + wv.w * __half2float(__ushort_as_half(q3.x));
                u.x = __half_as_ushort(__float2half_rn(a));
            }
            {
                const float a = wv.x * __half2float(__ushort_as_half(q0.y))
                              + wv.y * __half2float(__ushort_as_half(q1.y))
                              + wv.z * __half2float(__ushort_as_half(q2.y))
                              + wv.w * __half2float(__ushort_as_half(q3.y));
                u.y = __half_as_ushort(__float2half_rn(a));
            }
            {
                const float a = wv.x * __half2float(__ushort_as_half(q0.z))
                              + wv.y * __half2float(__ushort_as_half(q1.z))
                              + wv.z * __half2float(__ushort_as_half(q2.z))
                              + wv.w * __half2float(__ushort_as_half(q3.z));
                u.z = __half_as_ushort(__float2half_rn(a));
            }
            {
                const float a = wv.x * __half2float(__ushort_as_half(q0.w))
                              + wv.y * __half2float(__ushort_as_half(q1.w))
                              + wv.z * __half2float(__ushort_as_half(q2.w))
                              + wv.w * __half2float(__ushort_as_half(q3.w));
                u.w = __half_as_ushort(__float2half_rn(a));
            }
            *(ushort4*)&sVal[pos * GP2_ + cl] = u;
        }
    }
    __syncthreads();

    // half-box output: 128 c x 49 pos = 6272 floats, contiguous per block
    float* __restrict__ ob = out + (size_t)bn * CPB_ + (size_t)(ch * HCPB_);

    #pragma unroll
    for (int it = 0; it < 7; ++it) {
        const int flat4 = it * 256 + tid;     // float4 index, < 1568
        if (flat4 < 1568) {
            const int base = flat4 * 4;
            float4 v;
            {
                const int f = base + 0; const int cc = f / POS_; const int pp = f - cc * POS_;
                v.x = __half2float(__ushort_as_half(sVal[pp * GP2_ + cc]));
            }
            {
                const int f = base + 1; const int cc = f / POS_; const int pp = f - cc * POS_;
                v.y = __half2float(__ushort_as_half(sVal[pp * GP2_ + cc]));
            }
            {
                const int f = base + 2; const int cc = f / POS_; const int pp = f - cc * POS_;
                v.z = __half2float(__ushort_as_half(sVal[pp * GP2_ + cc]));
            }
            {
                const int f = base + 3; const int cc = f / POS_; const int pp = f - cc * POS_;
                v.w = __half2float(__ushort_as_half(sVal[pp * GP2_ + cc]));
            }
            *(float4*)(ob + base) = v;        // coalesced 16B store
        }
    }
}

// ---------------------------------------------------------------------------
// Fallback (R0 kernel): direct gather from (B,C,H,W) fp32 — used only if the
// workspace is too small for the fp16 transposed feature map.
// ---------------------------------------------------------------------------
__global__ __launch_bounds__(256) void rroi_align_fallback(
    const float* __restrict__ fm,
    const float* __restrict__ boxes,
    float* __restrict__ out)
{
    __shared__ int4   sOff[POS_];
    __shared__ float4 sWgt[POS_];

    const int bn  = blockIdx.x;
    const int b   = bn >> 9;
    const int tid = threadIdx.x;

    if (tid < POS_) {
        const float* bx = boxes + (size_t)bn * 5;
        const float cx = bx[0], cy = bx[1], w = bx[2], h = bx[3], ang = bx[4];
        const float rad = -ang * 0.017453292519943295f;
        const float cr = cosf(rad), sr = sinf(rad);
        const float a00 =  w * (1.0f / W_) * cr;
        const float a01 = -h * (1.0f / H_) * sr;
        const float a02 =  2.0f * cx * (1.0f / W_) - 1.0f;
        const float a10 =  w * (1.0f / W_) * sr;
        const float a11 =  h * (1.0f / H_) * cr;
        const float a12 =  2.0f * cy * (1.0f / H_) - 1.0f;
        const int py = tid / OW_;
        const int px = tid - py * OW_;
        const float xs = (2.0f * (float)px + 1.0f) / (float)OW_ - 1.0f;
        const float ys = (2.0f * (float)py + 1.0f) / (float)OH_ - 1.0f;
        const float gx = a00 * xs + a01 * ys + a02;
        const float gy = a10 * xs + a11 * ys + a12;
        const float ix = ((gx + 1.0f) * (float)W_ - 1.0f) * 0.5f;
        const float iy = ((gy + 1.0f) * (float)H_ - 1.0f) * 0.5f;
        const float x0f = floorf(ix), y0f = floorf(iy);
        const float wx1 = ix - x0f,  wy1 = iy - y0f;
        const float wx0 = 1.0f - wx1, wy0 = 1.0f - wy1;
        const float x1f = x0f + 1.0f, y1f = y0f + 1.0f;
        const float vx0 = (x0f >= 0.0f && x0f <= (float)(W_ - 1)) ? 1.0f : 0.0f;
        const float vx1 = (x1f >= 0.0f && x1f <= (float)(W_ - 1)) ? 1.0f : 0.0f;
        const float vy0 = (y0f >= 0.0f && y0f <= (float)(H_ - 1)) ? 1.0f : 0.0f;
        const float vy1 = (y1f >= 0.0f && y1f <= (float)(H_ - 1)) ? 1.0f : 0.0f;
        const int xi0 = (int)fminf(fmaxf(x0f, 0.0f), (float)(W_ - 1));
        const int xi1 = (int)fminf(fmaxf(x1f, 0.0f), (float)(W_ - 1));
        const int yi0 = (int)fminf(fmaxf(y0f, 0.0f), (float)(H_ - 1));
        const int yi1 = (int)fminf(fmaxf(y1f, 0.0f), (float)(H_ - 1));
        sOff[tid] = make_int4(yi0 * W_ + xi0, yi0 * W_ + xi1,
                              yi1 * W_ + xi0, yi1 * W_ + xi1);
        sWgt[tid] = make_float4(wy0 * wx0 * (vy0 * vx0),
                                wy0 * wx1 * (vy0 * vx1),
                                wy1 * wx0 * (vy1 * vx0),
                                wy1 * wx1 * (vy1 * vx1));
    }
    __syncthreads();

    const float* __restrict__ fb = fm + (size_t)b * C_ * HW_;
    float* __restrict__ ob = out + (size_t)bn * CPB_;

    #pragma unroll 7
    for (int it = 0; it < POS_; ++it) {
        const int flat = it * 256 + tid;
        const int cc   = flat / POS_;
        const int pos  = flat - cc * POS_;
        const int4   o  = sOff[pos];
        const float4 wv = sWgt[pos];
        const float* __restrict__ plane = fb + (size_t)cc * HW_;
        ob[flat] = wv.x * plane[o.x] + wv.y * plane[o.y]
                 + wv.z * plane[o.z] + wv.w * plane[o.w];
    }
}

extern "C" void kernel_launch(void* const* d_in, const int* in_sizes, int n_in,
                              void* d_out, int out_size, void* d_ws, size_t ws_size,
                              hipStream_t stream) {
    const float* fm    = (const float*)d_in[0];
    const float* boxes = (const float*)d_in[1];
    float* out         = (float*)d_out;

    const size_t needed = (size_t)B_ * C_ * HW_ * sizeof(ushort);  // 62.3 MB

    if (ws_size >= needed) {
        ushort* fmT = (ushort*)d_ws;
        transpose_f16_v5<<<dim3(1900), dim3(256), 0, stream>>>(fm, fmT);
        gather_f16_v3<<<dim3(2 * B_ * N_), dim3(256), 0, stream>>>(fmT, boxes, out);
    } else {
        rroi_align_fallback<<<dim3(B_ * N_), dim3(256), 0, stream>>>(fm, boxes, out);
    }
}